// Round 22
// baseline (151.996 us; speedup 1.0000x reference)
//
#include <hip/hip_runtime.h>
#include <hip/hip_bf16.h>

#define NROWS 65536
#define KDIM  512
constexpr float BN_EPS = 1e-5f;

using short8 = __attribute__((ext_vector_type(8))) short;
using f32x4  = __attribute__((ext_vector_type(4))) float;

#define BM 128   // rows per block
// cols per block = 256 (col-half); grid = (NROWS/BM) * 2

// async global->LDS, 16B per lane (dest MUST be uniform base + lane*16 — m104)
__device__ __forceinline__ void gload_lds16(const void* g, void* l) {
  __builtin_amdgcn_global_load_lds(
      (const __attribute__((address_space(1))) void*)g,
      (__attribute__((address_space(3))) void*)l, 16, 0, 0);
}

__device__ __forceinline__ short bf16bits(float x) {
  __hip_bfloat16 h = __float2bfloat16(x);    // RNE
  return *reinterpret_cast<short*>(&h);
}
__device__ __forceinline__ short8 cvt8(const float4& a, const float4& b) {
  short8 h;
  h[0] = bf16bits(a.x); h[1] = bf16bits(a.y); h[2] = bf16bits(a.z); h[3] = bf16bits(a.w);
  h[4] = bf16bits(b.x); h[5] = bf16bits(b.y); h[6] = bf16bits(b.z); h[7] = bf16bits(b.w);
  return h;
}

// ---------------- prep: C1 -> (kt, col-half)-tiled bf16 fragments ----------------
// entry (kt*2 + jh)*1024 + g*256 + c holds C1[(kt*4+g)*8 + i][jh*256 + c].
// Per (kt, jh) the 1024 entries (16 KB) are contiguous -> linear DMA staging.
__global__ __launch_bounds__(256)
void prep_c1(const float* __restrict__ C1, short8* __restrict__ c1tH) {
  const int e  = blockIdx.x * 256 + threadIdx.x;  // 0..32767
  const int kt = e >> 11;
  const int jh = (e >> 10) & 1;
  const int g  = (e >> 8) & 3;
  const int c  = e & 255;
  const int col = jh * 256 + c;
  short8 hi;
  #pragma unroll
  for (int i = 0; i < 8; ++i)
    hi[i] = bf16bits(C1[(size_t)((kt * 4 + g) * 8 + i) * KDIM + col]);
  c1tH[e] = hi;
}

// ---------------- quad: col-split blocks, 2 blk/CU, 3-buf counted-vmcnt ----------------
// Block (panel p, col-half jh) computes partial quad over 256 cols.
// 8 waves = 2 row-groups (64 rows) x 4 col-groups (64 cols); wave tile 64x64.
// LDS: Bs 3x16 KB (counted-vmcnt pipeline) + Asb 2x8 KB bf16 (reg-staged,
// written one phase ahead) = 66.5 KB -> 2 blocks/CU -> 4 waves/SIMD.
// Phase kt: issue {A(kt+1) 2 reg-loads, B(kt+2) 2 DMAs}; compute kt from LDS
// (4 A + 4 B ds_read_b128, 16 MFMA); vmcnt(2) [completes B(kt+1)+A(kt+1),
// leaves B(kt+2) in flight]; cvt+ds_write A(kt+1) -> Asb[(kt+1)&1];
// lgkmcnt(0); s_barrier. Asb layout [chunk][row]: both write and read 2-way.
__global__ __launch_bounds__(512, 4)
void quad_kernel(const float* __restrict__ X, const short8* __restrict__ c1tH,
                 float* __restrict__ quad,
                 float* __restrict__ colS1, float* __restrict__ colS2,
                 float* __restrict__ colS3) {
  __shared__ short8 Bs[3][1024];      // 3 x 16 KB
  __shared__ short8 Asb[2][512];      // 2 x 8 KB (entry g*128 + row)
  __shared__ float qPart[4][BM];
  __shared__ float qLds[BM];

  const int tid  = threadIdx.x;
  const int lane = tid & 63;
  const int w    = tid >> 6;          // wave 0..7
  const int wr   = w >> 2;            // row-group (0..1): rows wr*64..+63
  const int wc   = w & 3;             // col-group (0..3): 64 cols each
  const int g    = lane >> 4;         // k-group 0..3
  const int lr   = lane & 15;
  const int bid  = blockIdx.x;
  const int p    = bid >> 1;          // row panel
  const int jh   = bid & 1;           // col half
  const int r0   = p * BM;

  const short8* bsrc = c1tH + jh * 1024;
  // A staging: thread t -> row t>>2, k-chunk t&3; writes Asb entry chunk*128+row.
  const int arow = tid >> 2;
  const int ac   = tid & 3;
  const float* asrc = X + (size_t)(r0 + arow) * KDIM + ac * 8;
  const int adst = ac * 128 + arow;

#define STAGE_B(kt)                                                        \
  {                                                                        \
    gload_lds16(bsrc + (kt) * 2048 + tid,       &Bs[(kt) % 3][tid]);       \
    gload_lds16(bsrc + (kt) * 2048 + 512 + tid, &Bs[(kt) % 3][512 + tid]); \
  }

  f32x4 acc[4][4];
  #pragma unroll
  for (int rf = 0; rf < 4; ++rf)
    #pragma unroll
    for (int cf = 0; cf < 4; ++cf)
      acc[rf][cf] = (f32x4){0.f, 0.f, 0.f, 0.f};

  // ---- prologue: A(0) regs, B(0), B(1); vmcnt(2) -> A(0)+B(0) done, B(1) in flight ----
  {
    float4 a0 = *(const float4*)(asrc);
    float4 a1 = *(const float4*)(asrc + 4);
    STAGE_B(0);
    STAGE_B(1);
    asm volatile("s_waitcnt vmcnt(2)" ::: "memory");
    Asb[0][adst] = cvt8(a0, a1);
    asm volatile("s_waitcnt lgkmcnt(0)" ::: "memory");
    __builtin_amdgcn_s_barrier();
    __builtin_amdgcn_sched_barrier(0);
  }

  #pragma unroll
  for (int kt = 0; kt < 16; ++kt) {
    const int buf = kt % 3;
    float4 nr0, nr1;
    if (kt < 15) {
      nr0 = *(const float4*)(asrc + (kt + 1) * 32);
      nr1 = *(const float4*)(asrc + (kt + 1) * 32 + 4);
    }
    if (kt < 14) STAGE_B(kt + 2);

    // ---- A fragments (bf16, [chunk][row] layout: 2-way max) ----
    short8 Af[4];
    #pragma unroll
    for (int rf = 0; rf < 4; ++rf)
      Af[rf] = Asb[kt & 1][g * 128 + wr * 64 + rf * 16 + lr];
    // ---- B fragments + 16 MFMA ----
    const int fb = g * 256 + wc * 64 + lr;
    const short8 b0 = Bs[buf][fb];
    const short8 b1 = Bs[buf][fb + 16];
    const short8 b2 = Bs[buf][fb + 32];
    const short8 b3 = Bs[buf][fb + 48];
    #pragma unroll
    for (int rf = 0; rf < 4; ++rf) {
      acc[rf][0] = __builtin_amdgcn_mfma_f32_16x16x32_bf16(Af[rf], b0, acc[rf][0], 0, 0, 0);
      acc[rf][1] = __builtin_amdgcn_mfma_f32_16x16x32_bf16(Af[rf], b1, acc[rf][1], 0, 0, 0);
      acc[rf][2] = __builtin_amdgcn_mfma_f32_16x16x32_bf16(Af[rf], b2, acc[rf][2], 0, 0, 0);
      acc[rf][3] = __builtin_amdgcn_mfma_f32_16x16x32_bf16(Af[rf], b3, acc[rf][3], 0, 0, 0);
    }
    // ---- counted wait: B(kt+1)+A(kt+1) complete; B(kt+2) stays in flight ----
    if (kt < 15) {
      if (kt < 14) {
        asm volatile("s_waitcnt vmcnt(2)" ::: "memory");
      } else {
        asm volatile("s_waitcnt vmcnt(0)" ::: "memory");
      }
      Asb[(kt + 1) & 1][adst] = cvt8(nr0, nr1);
      asm volatile("s_waitcnt lgkmcnt(0)" ::: "memory");
      __builtin_amdgcn_s_barrier();
      __builtin_amdgcn_sched_barrier(0);
    }
  }
#undef STAGE_B

  // ---- epilogue: partial row-dot (this block's 256 cols) ----
  #pragma unroll
  for (int rf = 0; rf < 4; ++rf)
    #pragma unroll
    for (int pp = 0; pp < 4; ++pp) {
      const int row = wr * 64 + rf * 16 + g * 4 + pp;
      const float* xr = X + (size_t)(r0 + row) * KDIM + jh * 256 + wc * 64;
      float s = 0.f;
      #pragma unroll
      for (int cf = 0; cf < 4; ++cf)
        s += acc[rf][cf][pp] * xr[cf * 16 + lr];
      s += __shfl_xor(s, 1, 64);
      s += __shfl_xor(s, 2, 64);
      s += __shfl_xor(s, 4, 64);
      s += __shfl_xor(s, 8, 64);
      if (lr == 0) qPart[wc][row] = s;
    }
  __syncthreads();
  if (tid < BM) {
    const float q = qPart[0][tid] + qPart[1][tid] + qPart[2][tid] + qPart[3][tid];
    atomicAdd(&quad[r0 + tid], q);   // partial (this col-half)
    qLds[tid] = q;
  }
  __syncthreads();
  // ---- stats: colS3 += partial_q * x (sums correctly across halves);
  //      s1/s2 only from the jh==0 block (single count) ----
  {
    const int cb = (bid & 3) * 512;
    float s1 = 0.f, s2 = 0.f, s3 = 0.f;
    for (int r = 0; r < BM; ++r) {
      const float q = qLds[r];
      const float x = X[(size_t)(r0 + r) * KDIM + tid];
      s1 += x; s2 += x * x; s3 += q * x;
    }
    atomicAdd(&colS3[cb + tid], s3);
    if (jh == 0) {
      atomicAdd(&colS1[cb + tid], s1);
      atomicAdd(&colS2[cb + tid], s2);
    }
  }
}

// ---------------- qreduce: sum(q), sum(q^2) over the FINAL quad ----------------
__global__ __launch_bounds__(256)
void qreduce_kernel(const float* __restrict__ quad, double* __restrict__ qsumsA) {
  const int idx = blockIdx.x * 256 + threadIdx.x;     // 16384 float4's
  const float4 q4 = *(const float4*)&quad[idx * 4];
  double s  = (double)q4.x + (double)q4.y + (double)q4.z + (double)q4.w;
  double s2 = (double)q4.x * q4.x + (double)q4.y * q4.y +
              (double)q4.z * q4.z + (double)q4.w * q4.w;
  #pragma unroll
  for (int m = 1; m < 64; m <<= 1) {
    s  += __shfl_xor(s,  m, 64);
    s2 += __shfl_xor(s2, m, 64);
  }
  if ((threadIdx.x & 63) == 0) {
    atomicAdd(&qsumsA[0], s);
    atomicAdd(&qsumsA[1], s2);
  }
}

// ---------------- finalize per-feature mean / inv_std ----------------
__global__ void finalize_kernel(const float* __restrict__ colS1, const float* __restrict__ colS2,
                                const float* __restrict__ colS3, const double* __restrict__ qsumsA,
                                const float* __restrict__ C2, const float* __restrict__ C3,
                                float* __restrict__ mean, float* __restrict__ inv_std) {
  const int k = blockIdx.x * blockDim.x + threadIdx.x;
  if (k >= KDIM) return;
  const double invN = 1.0 / (double)NROWS;
  const double meanQ = qsumsA[0] * invN;
  const double varQ  = qsumsA[1] * invN - meanQ * meanQ;
  const float meanX = (colS1[k] + colS1[k + 512] + colS1[k + 1024] + colS1[k + 1536]) * (float)invN;
  const float s2    = (colS2[k] + colS2[k + 512] + colS2[k + 1024] + colS2[k + 1536]) * (float)invN;
  const float s3    = (colS3[k] + colS3[k + 512] + colS3[k + 1024] + colS3[k + 1536]) * (float)invN;
  const float varX  = s2 - meanX * meanX;
  const float covQX = s3 - (float)meanQ * meanX;
  const float c2 = C2[k];
  const float c3 = C3[0];
  const float m = (float)meanQ + c2 * meanX + c3;
  const float v = (float)varQ + c2 * c2 * varX + 2.0f * c2 * covQX;
  mean[k] = m;
  inv_std[k] = 1.0f / sqrtf(v + BN_EPS);
}

// ---------------- normalize + write ----------------
__global__ __launch_bounds__(256)
void normalize_kernel(const float* __restrict__ X, const float* __restrict__ quad,
                      const float* __restrict__ C2, const float* __restrict__ C3,
                      const float* __restrict__ mean, const float* __restrict__ inv_std,
                      float* __restrict__ out) {
  const int idx = blockIdx.x * blockDim.x + threadIdx.x;  // float4 index
  const int n = idx >> 7;
  const int j4 = idx & 127;
  const float q = quad[n];
  const float c3 = C3[0];
  const float4 x  = *(const float4*)&X[(size_t)idx * 4];
  const float4 c2 = *(const float4*)&C2[j4 * 4];
  const float4 m  = *(const float4*)&mean[j4 * 4];
  const float4 iv = *(const float4*)&inv_std[j4 * 4];
  float4 o;
  o.x = (q + c2.x * x.x + c3 - m.x) * iv.x;
  o.y = (q + c2.y * x.y + c3 - m.y) * iv.y;
  o.z = (q + c2.z * x.z + c3 - m.z) * iv.z;
  o.w = (q + c2.w * x.w + c3 - m.w) * iv.w;
  *(float4*)&out[(size_t)idx * 4] = o;
}

extern "C" void kernel_launch(void* const* d_in, const int* in_sizes, int n_in,
                              void* d_out, int out_size, void* d_ws, size_t ws_size,
                              hipStream_t stream) {
  const float* X  = (const float*)d_in[0];
  const float* C1 = (const float*)d_in[1];
  const float* C2 = (const float*)d_in[2];
  const float* C3 = (const float*)d_in[3];
  float* out = (float*)d_out;

  char* ws = (char*)d_ws;
  float*  quad    = (float*)ws;                           // 262144 B (zeroed; atomic target)
  float*  colS1   = (float*)(ws + 262144);                // 4 copies x 512 f
  float*  colS2   = (float*)(ws + 262144 + 8192);
  float*  colS3   = (float*)(ws + 262144 + 16384);
  double* qsumsA  = (double*)(ws + 262144 + 24576);       // 2 doubles
  float*  mean    = (float*)(ws + 262144 + 25088);
  float*  inv_std = (float*)(ws + 262144 + 27136);
  short8* c1tH    = (short8*)(ws + 294912);               // 512 KB, 16B-aligned

  // zero quad + colS + qsums in one contiguous memset
  hipMemsetAsync(ws, 0, 262144 + 24576 + 512, stream);

  prep_c1<<<128, 256, 0, stream>>>(C1, c1tH);
  quad_kernel<<<(NROWS / BM) * 2, 512, 0, stream>>>(X, c1tH, quad,
                                                    colS1, colS2, colS3);
  qreduce_kernel<<<64, 256, 0, stream>>>(quad, qsumsA);
  finalize_kernel<<<2, 256, 0, stream>>>(colS1, colS2, colS3, qsumsA, C2, C3, mean, inv_std);
  normalize_kernel<<<(NROWS * (KDIM / 4)) / 256, 256, 0, stream>>>(
      X, quad, C2, C3, mean, inv_std, out);
}